// Round 28
// baseline (152.948 us; speedup 1.0000x reference)
//
#include <hip/hip_runtime.h>
#include <math.h>

// Problem dims
#define BDIM 1024
#define RDIM 1152
#define IDIM 8
#define CDIM 10
#define ODIM 16
#define CO   160   // CDIM*ODIM

typedef _Float16 half_t;
typedef half_t f16x2 __attribute__((ext_vector_type(2)));
typedef half_t f16x4 __attribute__((ext_vector_type(4)));
typedef half_t f16x8 __attribute__((ext_vector_type(8)));
typedef float  f32x4 __attribute__((ext_vector_type(4)));

constexpr int RSPLIT = 48;                      // r splits in k_s (1152/48 = 24)
constexpr int R_PER_SPLIT = RDIM / RSPLIT;      // 24
constexpr int CH_R = 8;                         // r chunk per stage (2 MFMA k-steps)

// cvl LDS (f16): addr = rr*CVL_STRIDE + bb*10 + cc
// stride 328 f16 = 656 B; 656/4 mod 32 banks = 4 -> ~2-way on reads
constexpr int CVL_STRIDE = 328;
constexpr int CVL_SIZE = 7 * CVL_STRIDE + 31 * 10 + 10;   // 2616 f16

// workspace layout (in float units)
// bl stored TRANSPOSED (C, B, R) and in F16
constexpr size_t OFF_BL = 0;
constexpr size_t SZ_BL  = (size_t)BDIM * RDIM * CDIM / 2;     // 5,898,240 (f16)
constexpr size_t OFF_ST = OFF_BL + SZ_BL;                     // inv sumexp (B,C) f32
constexpr size_t SZ_ST  = (size_t)BDIM * CDIM;                // 10,240
constexpr size_t OFF_SP = OFF_ST + SZ_ST;                     // s partials (f16)
constexpr size_t SZ_SP  = (size_t)RSPLIT * BDIM * CO / 2;     // 3,932,160 (f16)
constexpr size_t OFF_SE = OFF_SP + SZ_SP;                     // sumexp partials [72][10][1024]
constexpr size_t SZ_SE  = (size_t)72 * CDIM * BDIM;           // 737,280
constexpr size_t OFF_WF = OFF_SE + SZ_SE;                     // k_s W frags (f16)
constexpr size_t SZ_WF  = 737280;                             // 184320*8 f16
constexpr size_t OFF_WA = OFF_WF + SZ_WF;                     // k_bT A frags (f16)
constexpr size_t SZ_WA  = 1474560;                            // 368640*8 f16 / 2
constexpr size_t OFF_VF = OFF_WA + SZ_WA;                     // k_bT B frags (f16)
constexpr size_t SZ_VF  = 163840;                             // 327680 f16 / 2
constexpr size_t OFF_VC = OFF_VF + SZ_VF;                     // v cumulative (f32)
constexpr size_t SZ_VC  = (size_t)BDIM * CO;                  // 163,840
constexpr size_t OFF_XF = OFF_VC + SZ_VC;                     // x in f16
constexpr size_t SZ_XF  = (size_t)BDIM * RDIM * IDIM / 2;     // 4,718,592
// total ~17.8 M floats = 71 MB

// ---------------------------------------------------------------------------
// k_prep: fused prep (one dispatch instead of four).
//  blocks [0,4608):    x f32 -> xf f16
//  blocks [4608,5328): WF frags (k_s B operand)
//  blocks [5328,6768): WA frags (k_bT A operand)
//  blocks [6768,6848): VF zero-half
// ---------------------------------------------------------------------------
__global__ __launch_bounds__(256) void k_prep(const float* __restrict__ x,
                                              const float* __restrict__ W,
                                              half_t* __restrict__ xf,
                                              half_t* __restrict__ WF,
                                              half_t* __restrict__ WA,
                                              half_t* __restrict__ VF) {
    const int blk = blockIdx.x, t = threadIdx.x;
    if (blk < 4608) {
        // xprep: 1,179,648 items x 8 floats
        size_t g = (size_t)blk * 256 + t;
        const float4 a = *(const float4*)(x + g * 8);
        const float4 b = *(const float4*)(x + g * 8 + 4);
        f16x8 h;
        h[0] = (half_t)a.x; h[1] = (half_t)a.y; h[2] = (half_t)a.z; h[3] = (half_t)a.w;
        h[4] = (half_t)b.x; h[5] = (half_t)b.y; h[6] = (half_t)b.z; h[7] = (half_t)b.w;
        *(f16x8*)(xf + g * 8) = h;
    } else if (blk < 5328) {
        // WF: WF[((rq*10+c)*64+l)*8+j] = (f16) W[rq*4+(l>>4)][i=j][c][o=l&15]
        int g = (blk - 4608) * 256 + t;       // 184320
        int lane = g & 63;
        int rc = g >> 6;
        int c = rc % 10;
        int rq = rc / 10;
        int r = rq * 4 + (lane >> 4);
        int o = lane & 15;
        const float* wp = W + (size_t)r * IDIM * CO + c * ODIM + o;
        f16x8 v;
#pragma unroll
        for (int j = 0; j < 8; ++j) v[j] = (half_t)wp[(size_t)j * CO];
        *(f16x8*)(WF + (size_t)g * 8) = v;
    } else if (blk < 6768) {
        // WA: row=l&15, m=mt*16+row, r=m>>3, i=m&7, kg=l>>4;
        // kg<2: (f16) W[r][i][c][o=kg*8+j] else 0
        int g = (blk - 5328) * 256 + t;       // 368640
        int l = g & 63;
        int mc = g >> 6;
        int c = mc % 10;
        int mt = mc / 10;
        int m = mt * 16 + (l & 15);
        int r = m >> 3, i = m & 7, kg = l >> 4;
        f16x8 v = {0, 0, 0, 0, 0, 0, 0, 0};
        if (kg < 2) {
            const float* wp = W + (size_t)r * 1280 + i * 160 + c * 16 + kg * 8;
#pragma unroll
            for (int j = 0; j < 8; ++j) v[j] = (half_t)wp[j];
        }
        *(f16x8*)(WA + (size_t)g * 8) = v;
    } else {
        // VF zero-half (l >= 32)
        int g = (blk - 6768) * 256 + t;       // 20480
        int l = 32 + (g & 31);
        int cb = g >> 5;
        *(f16x8*)(VF + ((size_t)cb * 64 + l) * 8) = (f16x8){0, 0, 0, 0, 0, 0, 0, 0};
    }
}

// ---------------------------------------------------------------------------
// k_s_mfma: s_part[split][b][c][o] = sum_{r in split} cval(b,r,c)*u_hat(b,r,c,o)
// MODE 0: cval = 1 (scaled 1/R at write); MODE 1: cval = exp(bl)*inv_sumexp
// cvl stored f16 -- cval was ALREADY f16-rounded before use (chf cast), so
// moving the cast to staging is bit-identical; halves cvl LDS and removes
// the per-MFMA-loop cvt.  bl f16 + consistent st (exact softmax of f16 logits).
// NOTE: cval MUST be normalized (<=1) before the f16 cast (R15 NaN lesson).
// ---------------------------------------------------------------------------
template <int MODE>
__global__ __launch_bounds__(256) void k_s_mfma(const half_t* __restrict__ xf,
                                                const half_t* __restrict__ WF,
                                                const half_t* __restrict__ bl,
                                                const float* __restrict__ stats,
                                                half_t* __restrict__ s_part) {
    __shared__ half_t xs[CH_R * 32 * IDIM];     // [rr][bb][i] f16, 4 KB
    __shared__ half_t cvl[CVL_SIZE];            // softmax coeffs f16, 5.2 KB
    __shared__ float sts[32 * CDIM];            // inv-sumexp tile, 1.25 KB
    const int t = threadIdx.x;
    const int l = t & 63, w = t >> 6;
    const int b0 = blockIdx.x * 32;
    const int rg0 = blockIdx.y * R_PER_SPLIT;
    const int cbase = (w & 1) * 5;
    const int bsub = w >> 1;
    const int row = l & 15;
    const int kg = l >> 4;

    if (MODE == 1) {
        for (int e = t; e < 32 * CDIM; e += 256)
            sts[e] = stats[(size_t)b0 * CDIM + e];
    }
    __syncthreads();

    f32x4 acc[5];
#pragma unroll
    for (int s = 0; s < 5; ++s) acc[s] = (f32x4){0.f, 0.f, 0.f, 0.f};

    for (int ch = 0; ch < R_PER_SPLIT / CH_R; ++ch) {
        const int r0c = rg0 + ch * CH_R;
        // stage 8r x 32b x 8i from xf16: one f16x8 per thread, coalesced
        {
            int bb = t >> 3, rr = t & 7;
            *(f16x8*)&xs[(rr * 32 + bb) * IDIM] =
                *(const f16x8*)(xf + ((size_t)(b0 + bb) * RDIM + r0c + rr) * 8);
        }
        if (MODE == 1) {
            // one run per (bb,cc): f16x8 covers rr=0..7 (contiguous r in bl);
            // cvl addr = rr*CVL_STRIDE + q, q = bb*10+cc; sts[q] read once.
            for (int q = t; q < 320; q += 256) {
                int bb = q / 10;
                const f16x8 b8 = *(const f16x8*)(
                    bl + ((size_t)(q - bb * 10) * BDIM + b0 + bb) * RDIM + r0c);
                float inv = sts[q];
#pragma unroll
                for (int j = 0; j < 8; ++j)
                    cvl[j * CVL_STRIDE + q] = (half_t)(__expf((float)b8[j]) * inv);
            }
        }
        __syncthreads();

#pragma unroll
        for (int rq = 0; rq < CH_R / 4; ++rq) {
            const int rr = rq * 4 + kg;
            const f16x8 xv = *(const f16x8*)&xs[(rr * 32 + bsub * 16 + row) * IDIM];
            const int rqg = (r0c >> 2) + rq;
#pragma unroll
            for (int s = 0; s < 5; ++s) {
                const int cc = cbase + s;
                half_t chf = (MODE == 1)
                    ? cvl[rr * CVL_STRIDE + (bsub * 16 + row) * 10 + cc]
                    : (half_t)1.0f;
                f16x8 av;
#pragma unroll
                for (int j = 0; j < 8; ++j) av[j] = xv[j] * chf;
                const f16x8 bv = *(const f16x8*)(
                    WF + ((size_t)(rqg * CDIM + cc) * 64 + l) * 8);
                acc[s] = __builtin_amdgcn_mfma_f32_16x16x32_f16(av, bv, acc[s], 0, 0, 0);
            }
        }
        __syncthreads();
    }

#pragma unroll
    for (int s = 0; s < 5; ++s) {
        const int cc = cbase + s;
#pragma unroll
        for (int reg = 0; reg < 4; ++reg) {
            float val = acc[s][reg];
            if (MODE == 0) val *= (1.0f / RDIM);
            int brow = b0 + bsub * 16 + kg * 4 + reg;
            s_part[((size_t)blockIdx.y * BDIM + brow) * CO + cc * ODIM + (l & 15)] =
                (half_t)val;
        }
    }
}

// ---------------------------------------------------------------------------
// k_squash<MODE>: s = sum partials (f16); v = (n/(n+1)) * s / sqrt(n).
// 2-wide: each thread owns an (o, o+1) pair -> f16x2 loads (24 instead of 48),
// norm reduce = local pair-add + 3 width-8 shuffles.  Same f32 add order
// over p; only the intra-norm reduction order changes (f32-rounding-level).
//  MODE 0: first iter -> vcum = v, emit VF frag
//  MODE 1: mid iter   -> vcum += v, emit VF frag
//  MODE 2: last iter  -> write v to out
// ---------------------------------------------------------------------------
template <int MODE>
__global__ __launch_bounds__(256) void k_squash(const half_t* __restrict__ s_part,
                                                float* __restrict__ vcum,
                                                half_t* __restrict__ VF,
                                                float* __restrict__ out) {
    int g = blockIdx.x * 256 + threadIdx.x;    // B*CO/2 = 81920 pairs
    int b = g / (CO / 2);
    int cp = g - b * (CO / 2);                 // pair index: c*8 + (o>>1)
    int co = cp * 2;                           // element index of even member
    float s0 = 0.f, s1 = 0.f;
#pragma unroll
    for (int p = 0; p < RSPLIT; ++p) {
        const f16x2 h2 = *(const f16x2*)(
            s_part + ((size_t)p * BDIM + b) * CO + co);
        s0 += (float)h2[0];
        s1 += (float)h2[1];
    }
    float sq = s0 * s0 + s1 * s1;
    sq += __shfl_xor(sq, 1, 8);
    sq += __shfl_xor(sq, 2, 8);
    sq += __shfl_xor(sq, 4, 8);
    float n = sq;
    float scale = (n / (n + 1.0f)) / sqrtf(n);
    float v0 = s0 * scale, v1 = s1 * scale;
    if (MODE == 2) {
        out[(size_t)b * CO + co] = v0;
        out[(size_t)b * CO + co + 1] = v1;
        return;
    }
    float c0, c1;
    if (MODE == 0) {
        c0 = v0; c1 = v1;
    } else {
        c0 = vcum[(size_t)b * CO + co] + v0;
        c1 = vcum[(size_t)b * CO + co + 1] + v1;
    }
    vcum[(size_t)b * CO + co] = c0;
    vcum[(size_t)b * CO + co + 1] = c1;
    // VF slot for (b, c, o): l=((o>>3)<<4)|(b&15), j=o&7  (o, o+1 share l and
    // adjacent j since o is even)
    int c = co >> 4, o = co & 15;
    int l2 = ((o >> 3) << 4) | (b & 15);
    half_t* vp = VF + ((size_t)(c * 64 + (b >> 4)) * 64 + l2) * 8 + (o & 7);
    *(f16x2*)vp = (f16x2){(half_t)c0, (half_t)c1};
}

// ---------------------------------------------------------------------------
// k_bT: bl[c][b][r] (f16) = sum_i x[b,r,i] * T_c[r*8+i][b],
//       T_c[m][b] = sum_o W[r,i,c,o] vcum[b,c,o]  via mfma_f32_16x16x32_f16.
// R27 structure: 128-thread blocks (2 waves), b-tile 32, 8-mt batched MFMAs,
// c-invariant xh hoisted to VGPRs, f16x4 copy-out, non-atomic spexp partials
// from the F16-ROUNDED bl values.  No prefetch (R25 lesson).
// ---------------------------------------------------------------------------
__global__ __launch_bounds__(128) void k_bT(const half_t* __restrict__ xf,
                                            const half_t* __restrict__ WA,
                                            const half_t* __restrict__ VF,
                                            half_t* __restrict__ bl,
                                            float* __restrict__ spexp) {
    __shared__ half_t xs[32][136];    // [b-local][r*8+i] f16, +8 pad (8.7 KB)
    __shared__ float tt[2][16][17];   // per-wave transpose tile (2.2 KB)
    const int t = threadIdx.x, l = t & 63, w = t >> 6;
    const int b0 = blockIdx.x * 32, r0 = blockIdx.y * 16;
    const int row = l & 15, kg = l >> 4;

    // stage x: 32 b x 16 r x 8 i from xf16 (f16x8 copies, coalesced)
    for (int e = t; e < 512; e += 128) {
        int bb = e >> 4, rr = e & 15;
        *(f16x8*)&xs[bb][rr * 8] =
            *(const f16x8*)(xf + ((size_t)(b0 + bb) * RDIM + r0 + rr) * 8);
    }
    __syncthreads();

    // hoist the c-invariant xh fragments (r_loc = mt*2+(kg>>1), i-half = kg&1)
    f16x4 xh[8];
#pragma unroll
    for (int mt = 0; mt < 8; ++mt) {
        const int r_loc = mt * 2 + (kg >> 1);
        xh[mt] = *(const f16x4*)&xs[w * 16 + row][r_loc * 8 + (kg & 1) * 4];
    }

    const int bt = (b0 >> 4) + w;               // global b-tile for this wave
    for (int c = 0; c < 10; ++c) {
        const f16x8 bf = *(const f16x8*)(VF + ((size_t)(c * 64 + bt) * 64 + l) * 8);
        // batch-load all 8 A-frags (L2-resident), then 8 independent MFMAs
        f16x8 af[8];
#pragma unroll
        for (int mt = 0; mt < 8; ++mt)
            af[mt] = *(const f16x8*)(
                WA + ((size_t)((blockIdx.y * 8 + mt) * 10 + c) * 64 + l) * 8);
        f32x4 d[8];
#pragma unroll
        for (int mt = 0; mt < 8; ++mt)
            d[mt] = __builtin_amdgcn_mfma_f32_16x16x32_f16(
                af[mt], bf, (f32x4){0.f, 0.f, 0.f, 0.f}, 0, 0, 0);
        // epilogues: D col b = l&15, row m-local = kg*4+reg;
        // r_loc = mt*2 + (kg>>1), i = (kg&1)*4 + reg
#pragma unroll
        for (int mt = 0; mt < 8; ++mt) {
            const int r_loc = mt * 2 + (kg >> 1);
            float pv = d[mt][0] * (float)xh[mt][0] + d[mt][1] * (float)xh[mt][1] +
                       d[mt][2] * (float)xh[mt][2] + d[mt][3] * (float)xh[mt][3];
            pv += __shfl_xor(pv, 16, 64);       // fold i-halves (kg0+kg1, kg2+kg3)
            if (!(kg & 1)) tt[w][r_loc][row] = pv;
        }
        // copy out 16r x 16b as f16 (lane bb=l>>2, rq=l&3 -> f16x4, 32-B r-runs)
        // + per-block sumexp partial from the ROUNDED values (consistency)
        {
            const int bb = l >> 2, rq = l & 3;
            f16x4 h4;
            h4[0] = (half_t)tt[w][rq * 4 + 0][bb];
            h4[1] = (half_t)tt[w][rq * 4 + 1][bb];
            h4[2] = (half_t)tt[w][rq * 4 + 2][bb];
            h4[3] = (half_t)tt[w][rq * 4 + 3][bb];
            size_t gi = ((size_t)c * BDIM + b0 + w * 16 + bb) * RDIM + r0 + rq * 4;
            *(f16x4*)(bl + gi) = h4;
            float pexp = __expf((float)h4[0]) + __expf((float)h4[1]) +
                         __expf((float)h4[2]) + __expf((float)h4[3]);
            pexp += __shfl_xor(pexp, 1, 4);
            pexp += __shfl_xor(pexp, 2, 4);
            if (rq == 0)
                spexp[((size_t)blockIdx.y * CDIM + c) * BDIM + b0 + w * 16 + bb] = pexp;
        }
    }
}

// ---------------------------------------------------------------------------
// k_stats_red: st[b*10+c] = 1 / sum_{ry=0..71} spexp[ry][c][b].
// 10240 threads; reads coalesced in b.
// ---------------------------------------------------------------------------
__global__ __launch_bounds__(256) void k_stats_red(const float* __restrict__ spexp,
                                                   float* __restrict__ st) {
    int g = blockIdx.x * 256 + threadIdx.x;    // c*1024 + b, 10240 total
    int c = g >> 10, b = g & 1023;
    float se = 0.f;
#pragma unroll 8
    for (int ry = 0; ry < 72; ++ry)
        se += spexp[((size_t)ry * CDIM + c) * BDIM + b];
    st[b * CDIM + c] = 1.0f / se;
}

// ---------------------------------------------------------------------------
extern "C" void kernel_launch(void* const* d_in, const int* in_sizes, int n_in,
                              void* d_out, int out_size, void* d_ws, size_t ws_size,
                              hipStream_t stream) {
    const float* x = (const float*)d_in[0];
    const float* W = (const float*)d_in[1];
    float* out = (float*)d_out;
    float* ws = (float*)d_ws;

    half_t* bl = (half_t*)(ws + OFF_BL);
    float* st = ws + OFF_ST;
    half_t* sp = (half_t*)(ws + OFF_SP);
    float* se = ws + OFF_SE;
    half_t* wf = (half_t*)(ws + OFF_WF);
    half_t* wa = (half_t*)(ws + OFF_WA);
    half_t* vf = (half_t*)(ws + OFF_VF);
    float* vc = ws + OFF_VC;
    half_t* xf = (half_t*)(ws + OFF_XF);

    dim3 gs(BDIM / 32, RSPLIT);                // 32 x 48 blocks of 256
    dim3 gb(BDIM / 32, RDIM / 16);             // 32 x 72 = 2304 blocks of 128
    const int gsq = (BDIM * CO / 2) / 256;     // 320 blocks

    k_prep<<<6848, 256, 0, stream>>>(x, W, xf, wf, wa, vf);

    // iteration 0: softmax(0) uniform -> s0 = mean_r u_hat
    k_s_mfma<0><<<gs, 256, 0, stream>>>(xf, wf, bl, st, sp);
    k_squash<0><<<gsq, 256, 0, stream>>>(sp, vc, vf, out);
    k_bT<<<gb, 128, 0, stream>>>(xf, wa, vf, bl, se);      // b1 + partials
    k_stats_red<<<40, 256, 0, stream>>>(se, st);

    // iteration 1
    k_s_mfma<1><<<gs, 256, 0, stream>>>(xf, wf, bl, st, sp);
    k_squash<1><<<gsq, 256, 0, stream>>>(sp, vc, vf, out);
    k_bT<<<gb, 128, 0, stream>>>(xf, wa, vf, bl, se);      // b2 + partials
    k_stats_red<<<40, 256, 0, stream>>>(se, st);

    // iteration 2 (final)
    k_s_mfma<1><<<gs, 256, 0, stream>>>(xf, wf, bl, st, sp);
    k_squash<2><<<gsq, 256, 0, stream>>>(sp, vc, vf, out);
}

// Round 29
// 151.807 us; speedup vs baseline: 1.0075x; 1.0075x over previous
//
#include <hip/hip_runtime.h>
#include <math.h>

// Problem dims
#define BDIM 1024
#define RDIM 1152
#define IDIM 8
#define CDIM 10
#define ODIM 16
#define CO   160   // CDIM*ODIM

typedef _Float16 half_t;
typedef half_t f16x4 __attribute__((ext_vector_type(4)));
typedef half_t f16x8 __attribute__((ext_vector_type(8)));
typedef float  f32x4 __attribute__((ext_vector_type(4)));

constexpr int RSPLIT = 48;                      // r splits in k_s (1152/48 = 24)
constexpr int R_PER_SPLIT = RDIM / RSPLIT;      // 24
constexpr int CH_R = 8;                         // r chunk per stage (2 MFMA k-steps)

// cvl LDS: addr = rr*324 + bb*10 + cc  (stride 324 = 4 mod 32 banks -> ~2-way)
constexpr int CVL_STRIDE = 324;
constexpr int CVL_SIZE = 7 * CVL_STRIDE + 31 * 10 + 10;   // 2588 floats

// workspace layout (in float units)
// bl stored TRANSPOSED (C, B, R) and in F16
constexpr size_t OFF_BL = 0;
constexpr size_t SZ_BL  = (size_t)BDIM * RDIM * CDIM / 2;     // 5,898,240 (f16)
constexpr size_t OFF_ST = OFF_BL + SZ_BL;                     // inv sumexp (B,C) f32
constexpr size_t SZ_ST  = (size_t)BDIM * CDIM;                // 10,240
constexpr size_t OFF_SP = OFF_ST + SZ_ST;                     // s partials (f16)
constexpr size_t SZ_SP  = (size_t)RSPLIT * BDIM * CO / 2;     // 3,932,160 (f16)
constexpr size_t OFF_SE = OFF_SP + SZ_SP;                     // sumexp partials [72][10][1024]
constexpr size_t SZ_SE  = (size_t)72 * CDIM * BDIM;           // 737,280
constexpr size_t OFF_WF = OFF_SE + SZ_SE;                     // k_s W frags (f16)
constexpr size_t SZ_WF  = 737280;                             // 184320*8 f16
constexpr size_t OFF_WA = OFF_WF + SZ_WF;                     // k_bT A frags (f16)
constexpr size_t SZ_WA  = 1474560;                            // 368640*8 f16 / 2
constexpr size_t OFF_VF = OFF_WA + SZ_WA;                     // k_bT B frags (f16)
constexpr size_t SZ_VF  = 163840;                             // 327680 f16 / 2
constexpr size_t OFF_VC = OFF_VF + SZ_VF;                     // v cumulative (f32)
constexpr size_t SZ_VC  = (size_t)BDIM * CO;                  // 163,840
constexpr size_t OFF_XF = OFF_VC + SZ_VC;                     // x in f16
constexpr size_t SZ_XF  = (size_t)BDIM * RDIM * IDIM / 2;     // 4,718,592
// total ~17.8 M floats = 71 MB

// ---------------------------------------------------------------------------
// k_prep: fused prep (one dispatch instead of four).
//  blocks [0,4608):    x f32 -> xf f16
//  blocks [4608,5328): WF frags (k_s B operand)
//  blocks [5328,6768): WA frags (k_bT A operand)
//  blocks [6768,6848): VF zero-half
// ---------------------------------------------------------------------------
__global__ __launch_bounds__(256) void k_prep(const float* __restrict__ x,
                                              const float* __restrict__ W,
                                              half_t* __restrict__ xf,
                                              half_t* __restrict__ WF,
                                              half_t* __restrict__ WA,
                                              half_t* __restrict__ VF) {
    const int blk = blockIdx.x, t = threadIdx.x;
    if (blk < 4608) {
        // xprep: 1,179,648 items x 8 floats
        size_t g = (size_t)blk * 256 + t;
        const float4 a = *(const float4*)(x + g * 8);
        const float4 b = *(const float4*)(x + g * 8 + 4);
        f16x8 h;
        h[0] = (half_t)a.x; h[1] = (half_t)a.y; h[2] = (half_t)a.z; h[3] = (half_t)a.w;
        h[4] = (half_t)b.x; h[5] = (half_t)b.y; h[6] = (half_t)b.z; h[7] = (half_t)b.w;
        *(f16x8*)(xf + g * 8) = h;
    } else if (blk < 5328) {
        // WF: WF[((rq*10+c)*64+l)*8+j] = (f16) W[rq*4+(l>>4)][i=j][c][o=l&15]
        int g = (blk - 4608) * 256 + t;       // 184320
        int lane = g & 63;
        int rc = g >> 6;
        int c = rc % 10;
        int rq = rc / 10;
        int r = rq * 4 + (lane >> 4);
        int o = lane & 15;
        const float* wp = W + (size_t)r * IDIM * CO + c * ODIM + o;
        f16x8 v;
#pragma unroll
        for (int j = 0; j < 8; ++j) v[j] = (half_t)wp[(size_t)j * CO];
        *(f16x8*)(WF + (size_t)g * 8) = v;
    } else if (blk < 6768) {
        // WA: row=l&15, m=mt*16+row, r=m>>3, i=m&7, kg=l>>4;
        // kg<2: (f16) W[r][i][c][o=kg*8+j] else 0
        int g = (blk - 5328) * 256 + t;       // 368640
        int l = g & 63;
        int mc = g >> 6;
        int c = mc % 10;
        int mt = mc / 10;
        int m = mt * 16 + (l & 15);
        int r = m >> 3, i = m & 7, kg = l >> 4;
        f16x8 v = {0, 0, 0, 0, 0, 0, 0, 0};
        if (kg < 2) {
            const float* wp = W + (size_t)r * 1280 + i * 160 + c * 16 + kg * 8;
#pragma unroll
            for (int j = 0; j < 8; ++j) v[j] = (half_t)wp[j];
        }
        *(f16x8*)(WA + (size_t)g * 8) = v;
    } else {
        // VF zero-half (l >= 32)
        int g = (blk - 6768) * 256 + t;       // 20480
        int l = 32 + (g & 31);
        int cb = g >> 5;
        *(f16x8*)(VF + ((size_t)cb * 64 + l) * 8) = (f16x8){0, 0, 0, 0, 0, 0, 0, 0};
    }
}

// ---------------------------------------------------------------------------
// k_s_mfma: s_part[split][b][c][o] = sum_{r in split} cval(b,r,c)*u_hat(b,r,c,o)
// MODE 0: cval = 1 (scaled 1/R at write); MODE 1: cval = exp(bl)*inv_sumexp
// bl is f16 (logits pre-rounded by k_bT; st computed from the SAME rounded
// values -> softmax weights are an exact softmax of the f16 logits).
// cvl staging vectorized: 320 f16x8 runs (one per (bb,cc), rr=0..7 contiguous
// in the (C,B,R) layout) -> 10x fewer loads/divisions than per-element.
// NOTE: cval MUST be normalized (<=1) before the f16 cast (R15 NaN lesson).
// ---------------------------------------------------------------------------
template <int MODE>
__global__ __launch_bounds__(256) void k_s_mfma(const half_t* __restrict__ xf,
                                                const half_t* __restrict__ WF,
                                                const half_t* __restrict__ bl,
                                                const float* __restrict__ stats,
                                                half_t* __restrict__ s_part) {
    __shared__ half_t xs[CH_R * 32 * IDIM];     // [rr][bb][i] f16, 4 KB
    __shared__ float cvl[CVL_SIZE];             // softmax coeffs, 10.4 KB
    __shared__ float sts[32 * CDIM];            // inv-sumexp tile, 1.25 KB
    const int t = threadIdx.x;
    const int l = t & 63, w = t >> 6;
    const int b0 = blockIdx.x * 32;
    const int rg0 = blockIdx.y * R_PER_SPLIT;
    const int cbase = (w & 1) * 5;
    const int bsub = w >> 1;
    const int row = l & 15;
    const int kg = l >> 4;

    if (MODE == 1) {
        for (int e = t; e < 32 * CDIM; e += 256)
            sts[e] = stats[(size_t)b0 * CDIM + e];
    }
    __syncthreads();

    f32x4 acc[5];
#pragma unroll
    for (int s = 0; s < 5; ++s) acc[s] = (f32x4){0.f, 0.f, 0.f, 0.f};

    for (int ch = 0; ch < R_PER_SPLIT / CH_R; ++ch) {
        const int r0c = rg0 + ch * CH_R;
        // stage 8r x 32b x 8i from xf16: one f16x8 per thread, coalesced
        {
            int bb = t >> 3, rr = t & 7;
            *(f16x8*)&xs[(rr * 32 + bb) * IDIM] =
                *(const f16x8*)(xf + ((size_t)(b0 + bb) * RDIM + r0c + rr) * 8);
        }
        if (MODE == 1) {
            // one run per (bb,cc): f16x8 covers rr=0..7 (contiguous r in bl);
            // cvl addr = rr*CVL_STRIDE + q, q = bb*10+cc; sts[q] read once.
            for (int q = t; q < 320; q += 256) {
                int bb = q / 10;
                const f16x8 b8 = *(const f16x8*)(
                    bl + ((size_t)(q - bb * 10) * BDIM + b0 + bb) * RDIM + r0c);
                float inv = sts[q];
#pragma unroll
                for (int j = 0; j < 8; ++j)
                    cvl[j * CVL_STRIDE + q] = __expf((float)b8[j]) * inv;
            }
        }
        __syncthreads();

#pragma unroll
        for (int rq = 0; rq < CH_R / 4; ++rq) {
            const int rr = rq * 4 + kg;
            const f16x8 xv = *(const f16x8*)&xs[(rr * 32 + bsub * 16 + row) * IDIM];
            const int rqg = (r0c >> 2) + rq;
#pragma unroll
            for (int s = 0; s < 5; ++s) {
                const int cc = cbase + s;
                float cval = (MODE == 1)
                    ? cvl[rr * CVL_STRIDE + (bsub * 16 + row) * 10 + cc] : 1.0f;
                half_t chf = (half_t)cval;
                f16x8 av;
#pragma unroll
                for (int j = 0; j < 8; ++j) av[j] = xv[j] * chf;
                const f16x8 bv = *(const f16x8*)(
                    WF + ((size_t)(rqg * CDIM + cc) * 64 + l) * 8);
                acc[s] = __builtin_amdgcn_mfma_f32_16x16x32_f16(av, bv, acc[s], 0, 0, 0);
            }
        }
        __syncthreads();
    }

#pragma unroll
    for (int s = 0; s < 5; ++s) {
        const int cc = cbase + s;
#pragma unroll
        for (int reg = 0; reg < 4; ++reg) {
            float val = acc[s][reg];
            if (MODE == 0) val *= (1.0f / RDIM);
            int brow = b0 + bsub * 16 + kg * 4 + reg;
            s_part[((size_t)blockIdx.y * BDIM + brow) * CO + cc * ODIM + (l & 15)] =
                (half_t)val;
        }
    }
}

// ---------------------------------------------------------------------------
// k_squash<MODE>: s = sum partials (f16); v = (n/(n+1)) * s / sqrt(n).
//  MODE 0: first iter -> vcum = v, emit VF frag
//  MODE 1: mid iter   -> vcum += v, emit VF frag
//  MODE 2: last iter  -> write v to out
// ---------------------------------------------------------------------------
template <int MODE>
__global__ __launch_bounds__(256) void k_squash(const half_t* __restrict__ s_part,
                                                float* __restrict__ vcum,
                                                half_t* __restrict__ VF,
                                                float* __restrict__ out) {
    int g = blockIdx.x * 256 + threadIdx.x;    // B*CO = 163840
    int b = g / CO;
    int co = g - b * CO;
    float s = 0.f;
#pragma unroll
    for (int p = 0; p < RSPLIT; ++p)
        s += (float)s_part[((size_t)p * BDIM + b) * CO + co];
    float sq = s * s;
    sq += __shfl_xor(sq, 1, 16);
    sq += __shfl_xor(sq, 2, 16);
    sq += __shfl_xor(sq, 4, 16);
    sq += __shfl_xor(sq, 8, 16);
    float n = sq;
    float val = (n / (n + 1.0f)) * s / sqrtf(n);
    if (MODE == 2) {
        out[g] = val;
        return;
    }
    float cum = (MODE == 0) ? val : vcum[g] + val;
    vcum[g] = cum;
    // VF fragment slot for element (b, c, o): l=((o>>3)<<4)|(b&15), j=o&7
    int c = co >> 4, o = co & 15;
    int l2 = ((o >> 3) << 4) | (b & 15);
    VF[((size_t)(c * 64 + (b >> 4)) * 64 + l2) * 8 + (o & 7)] = (half_t)cum;
}

// ---------------------------------------------------------------------------
// k_bT: bl[c][b][r] (f16) = sum_i x[b,r,i] * T_c[r*8+i][b],
//       T_c[m][b] = sum_o W[r,i,c,o] vcum[b,c,o]  via mfma_f32_16x16x32_f16.
// R24-proven structure + xh hoist: the 8 per-mt xs reads are c-invariant,
// so load them into 16 VGPRs once (80 -> 8 ds_reads per thread; shorter
// MFMA->epilogue chain).  No prefetch (R25 lesson).
// spexp partials from the F16-ROUNDED bl values (consistency).
// ---------------------------------------------------------------------------
__global__ __launch_bounds__(128) void k_bT(const half_t* __restrict__ xf,
                                            const half_t* __restrict__ WA,
                                            const half_t* __restrict__ VF,
                                            half_t* __restrict__ bl,
                                            float* __restrict__ spexp) {
    __shared__ half_t xs[32][136];    // [b-local][r*8+i] f16, +8 pad (8.7 KB)
    __shared__ float tt[2][16][17];   // per-wave transpose tile (2.2 KB)
    const int t = threadIdx.x, l = t & 63, w = t >> 6;
    const int b0 = blockIdx.x * 32, r0 = blockIdx.y * 16;
    const int row = l & 15, kg = l >> 4;

    // stage x: 32 b x 16 r x 8 i from xf16 (f16x8 copies, coalesced)
    for (int e = t; e < 512; e += 128) {
        int bb = e >> 4, rr = e & 15;
        *(f16x8*)&xs[bb][rr * 8] =
            *(const f16x8*)(xf + ((size_t)(b0 + bb) * RDIM + r0 + rr) * 8);
    }
    __syncthreads();

    // hoist the c-invariant xh fragments (r_loc = mt*2+(kg>>1), i-half = kg&1)
    f16x4 xh[8];
#pragma unroll
    for (int mt = 0; mt < 8; ++mt) {
        const int r_loc = mt * 2 + (kg >> 1);
        xh[mt] = *(const f16x4*)&xs[w * 16 + row][r_loc * 8 + (kg & 1) * 4];
    }

    const int bt = (b0 >> 4) + w;               // global b-tile for this wave
    for (int c = 0; c < 10; ++c) {
        const f16x8 bf = *(const f16x8*)(VF + ((size_t)(c * 64 + bt) * 64 + l) * 8);
        // batch-load all 8 A-frags (L2-resident), then 8 independent MFMAs
        f16x8 af[8];
#pragma unroll
        for (int mt = 0; mt < 8; ++mt)
            af[mt] = *(const f16x8*)(
                WA + ((size_t)((blockIdx.y * 8 + mt) * 10 + c) * 64 + l) * 8);
        f32x4 d[8];
#pragma unroll
        for (int mt = 0; mt < 8; ++mt)
            d[mt] = __builtin_amdgcn_mfma_f32_16x16x32_f16(
                af[mt], bf, (f32x4){0.f, 0.f, 0.f, 0.f}, 0, 0, 0);
        // epilogues: D col b = l&15, row m-local = kg*4+reg;
        // r_loc = mt*2 + (kg>>1), i = (kg&1)*4 + reg
#pragma unroll
        for (int mt = 0; mt < 8; ++mt) {
            const int r_loc = mt * 2 + (kg >> 1);
            float pv = d[mt][0] * (float)xh[mt][0] + d[mt][1] * (float)xh[mt][1] +
                       d[mt][2] * (float)xh[mt][2] + d[mt][3] * (float)xh[mt][3];
            pv += __shfl_xor(pv, 16, 64);       // fold i-halves (kg0+kg1, kg2+kg3)
            if (!(kg & 1)) tt[w][r_loc][row] = pv;
        }
        // copy out 16r x 16b as f16 (lane bb=l>>2, rq=l&3 -> f16x4, 32-B r-runs)
        // + per-block sumexp partial from the ROUNDED values (consistency)
        {
            const int bb = l >> 2, rq = l & 3;
            f16x4 h4;
            h4[0] = (half_t)tt[w][rq * 4 + 0][bb];
            h4[1] = (half_t)tt[w][rq * 4 + 1][bb];
            h4[2] = (half_t)tt[w][rq * 4 + 2][bb];
            h4[3] = (half_t)tt[w][rq * 4 + 3][bb];
            size_t gi = ((size_t)c * BDIM + b0 + w * 16 + bb) * RDIM + r0 + rq * 4;
            *(f16x4*)(bl + gi) = h4;
            float pexp = __expf((float)h4[0]) + __expf((float)h4[1]) +
                         __expf((float)h4[2]) + __expf((float)h4[3]);
            pexp += __shfl_xor(pexp, 1, 4);
            pexp += __shfl_xor(pexp, 2, 4);
            if (rq == 0)
                spexp[((size_t)blockIdx.y * CDIM + c) * BDIM + b0 + w * 16 + bb] = pexp;
        }
    }
}

// ---------------------------------------------------------------------------
// k_stats_red: st[b*10+c] = 1 / sum_{ry=0..71} spexp[ry][c][b].
// 10240 threads; reads coalesced in b.
// ---------------------------------------------------------------------------
__global__ __launch_bounds__(256) void k_stats_red(const float* __restrict__ spexp,
                                                   float* __restrict__ st) {
    int g = blockIdx.x * 256 + threadIdx.x;    // c*1024 + b, 10240 total
    int c = g >> 10, b = g & 1023;
    float se = 0.f;
#pragma unroll 8
    for (int ry = 0; ry < 72; ++ry)
        se += spexp[((size_t)ry * CDIM + c) * BDIM + b];
    st[b * CDIM + c] = 1.0f / se;
}

// ---------------------------------------------------------------------------
extern "C" void kernel_launch(void* const* d_in, const int* in_sizes, int n_in,
                              void* d_out, int out_size, void* d_ws, size_t ws_size,
                              hipStream_t stream) {
    const float* x = (const float*)d_in[0];
    const float* W = (const float*)d_in[1];
    float* out = (float*)d_out;
    float* ws = (float*)d_ws;

    half_t* bl = (half_t*)(ws + OFF_BL);
    float* st = ws + OFF_ST;
    half_t* sp = (half_t*)(ws + OFF_SP);
    float* se = ws + OFF_SE;
    half_t* wf = (half_t*)(ws + OFF_WF);
    half_t* wa = (half_t*)(ws + OFF_WA);
    half_t* vf = (half_t*)(ws + OFF_VF);
    float* vc = ws + OFF_VC;
    half_t* xf = (half_t*)(ws + OFF_XF);

    dim3 gs(BDIM / 32, RSPLIT);                // 32 x 48 blocks of 256
    dim3 gb(BDIM / 32, RDIM / 16);             // 32 x 72 = 2304 blocks of 128
    const int gsq = (BDIM * CO) / 256;         // 640 blocks

    k_prep<<<6848, 256, 0, stream>>>(x, W, xf, wf, wa, vf);

    // iteration 0: softmax(0) uniform -> s0 = mean_r u_hat
    k_s_mfma<0><<<gs, 256, 0, stream>>>(xf, wf, bl, st, sp);
    k_squash<0><<<gsq, 256, 0, stream>>>(sp, vc, vf, out);
    k_bT<<<gb, 128, 0, stream>>>(xf, wa, vf, bl, se);      // b1 + partials
    k_stats_red<<<40, 256, 0, stream>>>(se, st);

    // iteration 1
    k_s_mfma<1><<<gs, 256, 0, stream>>>(xf, wf, bl, st, sp);
    k_squash<1><<<gsq, 256, 0, stream>>>(sp, vc, vf, out);
    k_bT<<<gb, 128, 0, stream>>>(xf, wa, vf, bl, se);      // b2 + partials
    k_stats_red<<<40, 256, 0, stream>>>(se, st);

    // iteration 2 (final)
    k_s_mfma<1><<<gs, 256, 0, stream>>>(xf, wf, bl, st, sp);
    k_squash<2><<<gsq, 256, 0, stream>>>(sp, vc, vf, out);
}